// Round 6
// baseline (874.484 us; speedup 1.0000x reference)
//
#include <hip/hip_runtime.h>
#include <hip/hip_bf16.h>
#include <stdint.h>

// ---------------------------------------------------------------------------
// GCN encoder: src-octant binned scatter-add -> relu -> GEMM1(978->2048)
// + relu -> GEMM2(2048->100). bf16 MFMA for both GEMMs (fp32 accumulate).
//
// R8b: R7 pinned at ~3.3 TB/s with ~700MB of random xb-gather line fills
// (16MB table >> 4MB L2/XCD) dominating FETCH. Fix: two-level binning.
// Pass A streams edges into 8 src-octant regions (u64 entries, LDS full-line
// staging, nt stores). Pass B pins octant o to XCD o (bid%8): every gather
// hits a 2MB L2-resident xb slice; dst-binning keeps R7's full-line stage
// machinery. Overflow paths are hole-race-free (clamp + lossless spill).
// ebuf aliases the post-scatter buffers (agg/Abf/W1T/W2Tp/H1).
// (R8 compile fix: nt stores use ext_vector_type u32x4, not HIP uint4.)
// ---------------------------------------------------------------------------

typedef unsigned short u16;
typedef unsigned int u32;
typedef unsigned long long u64;
typedef __bf16 bf16x8 __attribute__((ext_vector_type(8)));
typedef float f32x4 __attribute__((ext_vector_type(4)));
typedef unsigned int u32x4 __attribute__((ext_vector_type(4)));

#define NGENES 978
#define KPAD   1024
#define H1DIM  2048
#define NOUT   100
#define NOUTP  112   // padded to 7 * 16
#define KSPLIT 8

// scatter binning: 8,011,776 nodes = 978 buckets x 8192 nodes (exact)
#define NB      978
#define BSH     13
#define BNODES  8192
#define SC_WGS  256     // pass B workgroups (32 per octant)
#define SC_THR  1024
#define SDEPTH  32      // pass B LDS stage depth per bucket
#define CAP_B   24576   // per-bucket pairs capacity (x16)

// src-octant binning (pass A)
#define NOCT     8
#define OCT_SH   20
#define OCT_NODES (1u << 20)
#define RSTRIDE  2686976u   // u64 entries per octant region (x8; mean 2.62M)
#define ODEPTH   512        // pass A LDS stage depth per octant
#define NWG_A    2048
#define A_THR    256

// round-to-nearest-even f32 -> bf16
__device__ __forceinline__ u16 f2b(float f) {
    unsigned u = __builtin_bit_cast(unsigned, f);
    u = (u + 0x7FFFu + ((u >> 16) & 1u)) >> 16;
    return (u16)u;
}

__device__ __forceinline__ u32 nt_u32(const u32* p) {
    return __builtin_nontemporal_load(p);
}
__device__ __forceinline__ float nt_f32(const float* p) {
    return __builtin_nontemporal_load(p);
}
__device__ __forceinline__ void nt_store4(u32x4 v, u32* p) {
    __builtin_nontemporal_store(v, (u32x4*)p);
}

// async 16B global -> LDS direct copy (wave-uniform base + lane*16 layout)
__device__ __forceinline__ void gl2lds16(const void* g, void* l) {
    __builtin_amdgcn_global_load_lds(
        (const __attribute__((address_space(1))) void*)(uintptr_t)g,
        (__attribute__((address_space(3))) void*)(unsigned)(uintptr_t)l,
        16, 0, 0);
}

// ---------------------------------------------------------------------------
// Detect whether edges buffer is int64 (odd 4-byte words all zero) or int32.
// ---------------------------------------------------------------------------
__global__ void detect_kernel(const unsigned* __restrict__ e, int* __restrict__ flag) {
    if (threadIdx.x == 0) {
        int is64 = 1;
        for (int i = 0; i < 64; ++i) {
            if (e[2 * i + 1] != 0u) { is64 = 0; break; }
        }
        *flag = is64;
    }
}

// ---------------------------------------------------------------------------
// xb[n] = bf16(inputs[n] * gcn_w) — the gather table (16 MB).
// ---------------------------------------------------------------------------
__global__ void xbf_kernel(const float* __restrict__ x, const float* __restrict__ gcn_w,
                           u16* __restrict__ xb, int N) {
    const float w = gcn_w[0];
    int i = (blockIdx.x * 256 + threadIdx.x) * 4;
    if (i + 3 < N) {
        float4 v = *(const float4*)&x[i];
        xb[i + 0] = f2b(v.x * w);
        xb[i + 1] = f2b(v.y * w);
        xb[i + 2] = f2b(v.z * w);
        xb[i + 3] = f2b(v.w * w);
    } else {
        for (int k = i; k < N; ++k) xb[k] = f2b(x[k] * w);
    }
}

// ---------------------------------------------------------------------------
// Pass A: stream edges, bin u64 entries ((dst<<20)|src_local) by src-octant
// (o = src>>20). LDS stage [8][512], flush 8-entry 64B groups (nt) at
// globally reserved positions. Hole-race-free: no atomicSub; counter clamped
// at flush; overflow spills losslessly to ovfe (fixed after accum).
// ---------------------------------------------------------------------------
__global__ __launch_bounds__(A_THR) void binoct_kernel(const void* __restrict__ edges,
                                                       const int* __restrict__ flag, int E,
                                                       u64* __restrict__ ebuf,
                                                       u32* __restrict__ ocnt,
                                                       u64* __restrict__ ovfe,
                                                       u32* __restrict__ ovfecnt) {
    __shared__ u64 stA[NOCT][ODEPTH];   // 32 KB
    __shared__ u32 ofill[NOCT];
    __shared__ u32 gbase[NOCT], gn[NOCT];
    const int tid = threadIdx.x;
    if (tid < NOCT) ofill[tid] = 0;
    __syncthreads();

    const int per = (E + NWG_A - 1) / NWG_A;
    const int s = blockIdx.x * per;
    const int e = min(E, s + per);
    const u32* eb = (const u32*)edges;
    const int st = (*flag) ? 2 : 1;
    const u32* sp = eb;
    const u32* dp = eb + (size_t)st * E;

    for (int base_i = s; base_i < e; base_i += 8 * A_THR) {
        u32 sv[8], dv[8];
#pragma unroll
        for (int k = 0; k < 8; ++k) {
            int i = base_i + tid + k * A_THR;
            bool ok = i < e;
            sv[k] = ok ? nt_u32(&sp[(size_t)st * i]) : 0xFFFFFFFFu;
            dv[k] = ok ? nt_u32(&dp[(size_t)st * i]) : 0u;
        }
#pragma unroll
        for (int k = 0; k < 8; ++k) {
            if (sv[k] != 0xFFFFFFFFu) {
                u32 o = sv[k] >> OCT_SH;
                u64 ent = ((u64)dv[k] << OCT_SH) | (u64)(sv[k] & (OCT_NODES - 1));
                u32 slot = atomicAdd(&ofill[o], 1u);
                if (slot < ODEPTH) {
                    stA[o][slot] = ent;
                } else {   // lossless spill: (dst<<32)|src_global
                    u32 og = atomicAdd(ovfecnt, 1u);
                    ovfe[og] = ((u64)dv[k] << 32) | (u64)sv[k];
                }
            }
        }
        __syncthreads();
        if (tid < NOCT) {
            u32 f = min(ofill[tid], (u32)ODEPTH);
            u32 nl = f >> 3;
            gn[tid] = nl;
            gbase[tid] = nl ? atomicAdd(&ocnt[tid], nl << 3) : 0u;
        }
        __syncthreads();
        {
            const int b = tid >> 5;          // 256 thr -> 8 bins x 32 lanes
            const u32 g0 = tid & 31;
            for (u32 g = g0; g < gn[b]; g += 32) {
                u32 base = gbase[b] + (g << 3);
                if (base < RSTRIDE) {
                    u64* dst = &ebuf[(size_t)b * RSTRIDE + base];
#pragma unroll
                    for (int q = 0; q < 4; ++q) {
                        u64 w0 = stA[b][g * 8 + q * 2];
                        u64 w1 = stA[b][g * 8 + q * 2 + 1];
                        u32x4 v;
                        v.x = (u32)w0; v.y = (u32)(w0 >> 32);
                        v.z = (u32)w1; v.w = (u32)(w1 >> 32);
                        nt_store4(v, (u32*)&dst[q * 2]);
                    }
                } else {   // region capacity spill (~never)
                    for (int q = 0; q < 8; ++q) {
                        u64 ent = stA[b][g * 8 + q];
                        u32 d = (u32)(ent >> OCT_SH);
                        u32 srcg = ((u32)b << OCT_SH) | ((u32)ent & (OCT_NODES - 1));
                        u32 og = atomicAdd(ovfecnt, 1u);
                        ovfe[og] = ((u64)d << 32) | (u64)srcg;
                    }
                }
            }
        }
        __syncthreads();
        if (tid < NOCT) {
            u32 f = min(ofill[tid], (u32)ODEPTH);
            u32 n8 = gn[tid] << 3;
            for (u32 r = n8; r < f; ++r) stA[tid][r - n8] = stA[tid][r];
            ofill[tid] = f - n8;
        }
        __syncthreads();
    }
    // tail: one sentinel-padded group per octant (keeps cursor x8-aligned)
    if (tid < NOCT) {
        u32 f = min(ofill[tid], (u32)ODEPTH);   // <= 7
        if (f) {
            u32 base = atomicAdd(&ocnt[tid], 8u);
            if (base < RSTRIDE) {
                u64* dst = &ebuf[(size_t)tid * RSTRIDE + base];
                for (u32 q = 0; q < 8; ++q)
                    dst[q] = (q < f) ? stA[tid][q] : ~0ull;
            } else {
                for (u32 q = 0; q < f; ++q) {
                    u64 ent = stA[tid][q];
                    u32 d = (u32)(ent >> OCT_SH);
                    u32 srcg = ((u32)tid << OCT_SH) | ((u32)ent & (OCT_NODES - 1));
                    u32 og = atomicAdd(ovfecnt, 1u);
                    ovfe[og] = ((u64)d << 32) | (u64)srcg;
                }
            }
        }
    }
}

// ---------------------------------------------------------------------------
// Pass B: per-octant gather + dst-bin. bid%8 = octant (XCD-pinned -> 2MB xb
// slice is L2-resident). Entry stream nt; pairs flushed as 64B nt bursts at
// globally reserved positions. Hole-race-free overflow -> ovfg spill.
// ---------------------------------------------------------------------------
__global__ __launch_bounds__(SC_THR) void binscatter_kernel(const u64* __restrict__ ebuf,
                                                            const u32* __restrict__ ocnt,
                                                            const u16* __restrict__ xb,
                                                            u32* __restrict__ pairs,
                                                            u32* __restrict__ cnt,
                                                            u32* __restrict__ ovfg,
                                                            u32* __restrict__ ovfcnt) {
    __shared__ u32 sfill[NB];
    __shared__ u32 stage[SDEPTH * NB];      // transposed [slot][bucket], 125 KB
    const int tid = threadIdx.x;
    for (int b = tid; b < NB; b += SC_THR) sfill[b] = 0;
    __syncthreads();

    const int o = blockIdx.x & 7;           // XCD pin
    const int sub = blockIdx.x >> 3;        // 0..31
    u32 n = ocnt[o]; if (n > RSTRIDE) n = RSTRIDE;
    const u64* eo = ebuf + (size_t)o * RSTRIDE;
    const u16* xbo = xb + ((size_t)o << OCT_SH);
    const u32 per = (n + 31) / 32;
    const u32 s = sub * per;
    const u32 e = min(n, s + per);

    for (u32 base_i = s; base_i < e; base_i += 8 * SC_THR) {
        u64 ev[8];
#pragma unroll
        for (int k = 0; k < 8; ++k) {
            u32 i = base_i + tid + k * SC_THR;
            ev[k] = (i < e) ? __builtin_nontemporal_load(&eo[i]) : ~0ull;
        }
        u32 d[8];
        u16 val[8];
#pragma unroll
        for (int k = 0; k < 8; ++k) {
            d[k] = (u32)(ev[k] >> OCT_SH);
            val[k] = (ev[k] != ~0ull) ? xbo[(u32)ev[k] & (OCT_NODES - 1)] : (u16)0;
        }
#pragma unroll
        for (int h = 0; h < 2; ++h) {
#pragma unroll
            for (int k = 4 * h; k < 4 * h + 4; ++k) {
                if (ev[k] != ~0ull) {
                    u32 b = d[k] >> BSH;
                    u32 pr = ((d[k] & (BNODES - 1)) << 16) | (u32)val[k];
                    u32 slot = atomicAdd(&sfill[b], 1u);
                    if (slot < SDEPTH) {
                        stage[slot * NB + b] = pr;
                    } else {   // lossless spill (dst_global, val)
                        u32 og = atomicAdd(ovfcnt, 1u);
                        ovfg[og * 2] = d[k];
                        ovfg[og * 2 + 1] = pr & 0xFFFFu;
                    }
                }
            }
            __syncthreads();
            for (int b = tid; b < NB; b += SC_THR) {
                u32 f = min(sfill[b], (u32)SDEPTH);   // clamp inflation
                u32 nl = f >> 4;
                if (nl) {
                    u32 base = atomicAdd(&cnt[b], nl << 4);
                    for (u32 g = 0; g < nl; ++g) {
                        u32 wb = base + (g << 4);
                        if (wb < CAP_B) {
                            u32* dst = &pairs[(size_t)b * CAP_B + wb];
#pragma unroll
                            for (int q = 0; q < 4; ++q) {
                                u32x4 v;
                                v.x = stage[(g * 16 + q * 4 + 0) * NB + b];
                                v.y = stage[(g * 16 + q * 4 + 1) * NB + b];
                                v.z = stage[(g * 16 + q * 4 + 2) * NB + b];
                                v.w = stage[(g * 16 + q * 4 + 3) * NB + b];
                                nt_store4(v, &dst[q * 4]);
                            }
                        } else {
                            for (int q = 0; q < 16; ++q) {
                                u32 pr = stage[(g * 16 + q) * NB + b];
                                u32 og = atomicAdd(ovfcnt, 1u);
                                ovfg[og * 2] = ((u32)b << BSH) | (pr >> 16);
                                ovfg[og * 2 + 1] = pr & 0xFFFFu;
                            }
                        }
                    }
                    u32 n16 = nl << 4;
                    u32 rem = f - n16;
                    for (u32 r = 0; r < rem; ++r)
                        stage[r * NB + b] = stage[(n16 + r) * NB + b];
                    sfill[b] = rem;
                } else {
                    sfill[b] = f;
                }
            }
            __syncthreads();
        }
    }
    // tail: flush remainder, zero-padded to x16 groups
    for (int b = tid; b < NB; b += SC_THR) {
        u32 f = min(sfill[b], (u32)SDEPTH);
        if (f) {
            u32 padded = (f + 15u) & ~15u;
            u32 base = atomicAdd(&cnt[b], padded);
            for (u32 g = 0; g < (padded >> 4); ++g) {
                u32 wb = base + (g << 4);
                if (wb < CAP_B) {
                    u32* dst = &pairs[(size_t)b * CAP_B + wb];
#pragma unroll
                    for (int q = 0; q < 4; ++q) {
                        u32x4 v;
                        u32 j = g * 16 + q * 4;
                        v.x = (j + 0 < f) ? stage[(j + 0) * NB + b] : 0u;
                        v.y = (j + 1 < f) ? stage[(j + 1) * NB + b] : 0u;
                        v.z = (j + 2 < f) ? stage[(j + 2) * NB + b] : 0u;
                        v.w = (j + 3 < f) ? stage[(j + 3) * NB + b] : 0u;
                        nt_store4(v, &dst[q * 4]);
                    }
                } else {
                    for (u32 q = g * 16; q < f && q < g * 16 + 16; ++q) {
                        u32 pr = stage[q * NB + b];
                        u32 og = atomicAdd(ovfcnt, 1u);
                        ovfg[og * 2] = ((u32)b << BSH) | (pr >> 16);
                        ovfg[og * 2 + 1] = pr & 0xFFFFu;
                    }
                }
            }
        }
    }
}

// ---------------------------------------------------------------------------
// Accum: per-bucket LDS fp32 tile, stream pairs (nt), write agg.
// ---------------------------------------------------------------------------
__global__ __launch_bounds__(512) void accum_kernel(const u32* __restrict__ pairs,
                                                    const u32* __restrict__ cnt,
                                                    float* __restrict__ agg) {
    __shared__ float acc[BNODES];    // 32 KB
    for (int i = threadIdx.x; i < BNODES; i += 512) acc[i] = 0.f;
    __syncthreads();
    const int b = blockIdx.x;
    u32 n = cnt[b];
    if (n > CAP_B) n = CAP_B;
    const u32 p0 = (u32)b * CAP_B;
    const u32 p1 = p0 + n;
    u32 p = p0 + threadIdx.x;
    for (; p + 3 * 512 < p1; p += 4 * 512) {
        u32 pk[4];
#pragma unroll
        for (int k = 0; k < 4; ++k) pk[k] = nt_u32(&pairs[p + k * 512]);
#pragma unroll
        for (int k = 0; k < 4; ++k) {
            if (pk[k]) {
                float v = __builtin_bit_cast(float, (pk[k] & 0xFFFFu) << 16);
                atomicAdd(&acc[pk[k] >> 16], v);
            }
        }
    }
    for (; p < p1; p += 512) {
        u32 pk = nt_u32(&pairs[p]);
        if (pk) {
            float v = __builtin_bit_cast(float, (pk & 0xFFFFu) << 16);
            atomicAdd(&acc[pk >> 16], v);
        }
    }
    __syncthreads();
    const size_t node0 = (size_t)b << BSH;
    for (int i = threadIdx.x; i < BNODES; i += 512) agg[node0 + i] = acc[i];
}

// ---------------------------------------------------------------------------
// Spill cleanups (run after accum; normally zero entries).
// ---------------------------------------------------------------------------
__global__ void ovf_fix_kernel(const u32* __restrict__ ovfg, const u32* __restrict__ ovfcnt,
                               float* __restrict__ agg) {
    u32 n = *ovfcnt;
    for (u32 i = blockIdx.x * 256 + threadIdx.x; i < n; i += gridDim.x * 256) {
        float v = __builtin_bit_cast(float, ovfg[i * 2 + 1] << 16);
        atomicAdd(&agg[ovfg[i * 2]], v);
    }
}

__global__ void ovfe_fix_kernel(const u64* __restrict__ ovfe, const u32* __restrict__ ovfecnt,
                                const u16* __restrict__ xb, float* __restrict__ agg) {
    u32 n = *ovfecnt;
    for (u32 i = blockIdx.x * 256 + threadIdx.x; i < n; i += gridDim.x * 256) {
        u64 ev = ovfe[i];
        u32 srcg = (u32)ev;
        u32 d = (u32)(ev >> 32);
        float v = __builtin_bit_cast(float, ((u32)xb[srcg]) << 16);
        atomicAdd(&agg[d], v);
    }
}

// ---------------------------------------------------------------------------
// Legacy direct-atomic scatter (fallback if workspace too small).
// ---------------------------------------------------------------------------
__global__ void scatter_kernel(const void* __restrict__ edges, const float* __restrict__ x,
                               const float* __restrict__ gcn_w, float* __restrict__ agg,
                               const int* __restrict__ flag, int E) {
    long long e = (long long)blockIdx.x * 256 + threadIdx.x;
    if (e >= E) return;
    int s, d;
    if (*flag) {
        const long long* e64 = (const long long*)edges;
        s = (int)e64[e];
        d = (int)e64[(long long)E + e];
    } else {
        const int* e32 = (const int*)edges;
        s = e32[e];
        d = e32[(long long)E + e];
    }
    atomicAdd(&agg[d], x[s] * gcn_w[0]);
}

// ---------------------------------------------------------------------------
// Fused bias + relu + bf16 convert, pad K 978 -> 1024 with zeros.
// ---------------------------------------------------------------------------
__global__ void act_kernel(const float* __restrict__ agg, const float* __restrict__ gcn_b,
                           u16* __restrict__ A) {
    int idx = blockIdx.x * 256 + threadIdx.x;
    int i = idx >> 10;         // KPAD = 1024
    int k = idx & 1023;
    float v = 0.f;
    if (k < NGENES) {
        v = nt_f32(&agg[(size_t)i * NGENES + k]) + gcn_b[0];
        v = v > 0.f ? v : 0.f;
    }
    A[idx] = f2b(v);
}

// ---------------------------------------------------------------------------
// W1 [978][2048] f32 -> W1T [2048][1024] bf16 (transposed, K zero-padded)
// ---------------------------------------------------------------------------
__global__ void transposeW1(const float* __restrict__ W1, u16* __restrict__ W1T) {
    __shared__ float t[32][33];
    int n0 = blockIdx.x * 32;
    int k0 = blockIdx.y * 32;
    int tx = threadIdx.x, ty = threadIdx.y;
    for (int r = ty; r < 32; r += 8) {
        int k = k0 + r;
        t[r][tx] = (k < NGENES) ? W1[(size_t)k * H1DIM + n0 + tx] : 0.f;
    }
    __syncthreads();
    for (int r = ty; r < 32; r += 8) {
        int n = n0 + r;
        W1T[(size_t)n * KPAD + k0 + tx] = f2b(t[tx][r]);
    }
}

// ---------------------------------------------------------------------------
// W2 [2048][100] f32 -> W2T [112][2048] bf16 (transposed, N zero-padded)
// ---------------------------------------------------------------------------
__global__ void transposeW2(const float* __restrict__ W2, u16* __restrict__ W2T) {
    __shared__ float t[32][33];
    int n0 = blockIdx.x * 32;
    int k0 = blockIdx.y * 32;
    int tx = threadIdx.x, ty = threadIdx.y;
    for (int r = ty; r < 32; r += 8) {
        int k = k0 + r;
        int n = n0 + tx;
        t[r][tx] = (n < NOUT) ? W2[(size_t)k * NOUT + n] : 0.f;
    }
    __syncthreads();
    for (int r = ty; r < 32; r += 8) {
        int n = n0 + r;
        if (n < NOUTP) W2T[(size_t)n * H1DIM + k0 + tx] = f2b(t[tx][r]);
    }
}

// ---------------------------------------------------------------------------
// GEMM1: H[8192][2048] = relu(A[8192][1024] @ W1T^T + b1), bf16 out.
// ---------------------------------------------------------------------------
__global__ __launch_bounds__(256) void gemm1_kernel(const u16* __restrict__ A,
                                                    const u16* __restrict__ Bt,
                                                    const float* __restrict__ b1,
                                                    u16* __restrict__ H) {
    __shared__ u16 As[128 * 32];
    __shared__ u16 Bs[128 * 32];
    const int tid = threadIdx.x;
    const int m0 = blockIdx.y * 128;
    const int n0 = blockIdx.x * 128;
    const int wave = tid >> 6;
    const int lane = tid & 63;
    const int wm = (wave >> 1) * 64;
    const int wn = (wave & 1) * 64;
    const int quad = lane >> 4;
    const int l16 = lane & 15;

    f32x4 acc[4][4];
#pragma unroll
    for (int i = 0; i < 4; ++i)
#pragma unroll
        for (int j = 0; j < 4; ++j)
            acc[i][j] = (f32x4){0.f, 0.f, 0.f, 0.f};

    const int ch0 = tid, ch1 = tid + 256;
    const u16* ag0 = A + (size_t)(m0 + (ch0 >> 2)) * KPAD + (ch0 & 3) * 8;
    const u16* ag1 = A + (size_t)(m0 + (ch1 >> 2)) * KPAD + (ch1 & 3) * 8;
    const u16* bg0 = Bt + (size_t)(n0 + (ch0 >> 2)) * KPAD + (ch0 & 3) * 8;
    const u16* bg1 = Bt + (size_t)(n0 + (ch1 >> 2)) * KPAD + (ch1 & 3) * 8;
    u16* la0 = &As[ch0 * 8];
    u16* la1 = &As[ch1 * 8];
    u16* lb0 = &Bs[ch0 * 8];
    u16* lb1 = &Bs[ch1 * 8];

    for (int k0 = 0; k0 < KPAD; k0 += 32) {
        gl2lds16(ag0, la0);
        gl2lds16(ag1, la1);
        gl2lds16(bg0, lb0);
        gl2lds16(bg1, lb1);
        ag0 += 32; ag1 += 32; bg0 += 32; bg1 += 32;
        __syncthreads();

        bf16x8 af[4], bfr[4];
#pragma unroll
        for (int i = 0; i < 4; ++i)
            af[i] = *(const bf16x8*)&As[(wm + i * 16 + l16) * 32 + quad * 8];
#pragma unroll
        for (int j = 0; j < 4; ++j)
            bfr[j] = *(const bf16x8*)&Bs[(wn + j * 16 + l16) * 32 + quad * 8];
#pragma unroll
        for (int i = 0; i < 4; ++i)
#pragma unroll
            for (int j = 0; j < 4; ++j)
                acc[i][j] = __builtin_amdgcn_mfma_f32_16x16x32_bf16(af[i], bfr[j], acc[i][j], 0, 0, 0);
        __syncthreads();
    }

#pragma unroll
    for (int j = 0; j < 4; ++j) {
        const int col = n0 + wn + j * 16 + l16;
        const float bv = b1[col];
#pragma unroll
        for (int i = 0; i < 4; ++i) {
            const int rbase = m0 + wm + i * 16 + quad * 4;
#pragma unroll
            for (int r = 0; r < 4; ++r) {
                float v = acc[i][j][r] + bv;
                v = v > 0.f ? v : 0.f;
                H[(size_t)(rbase + r) * H1DIM + col] = f2b(v);
            }
        }
    }
}

// ---------------------------------------------------------------------------
// GEMM2: out[8192][100] += H[8192][2048] @ W2T^T + b2, split-K with atomics.
// ---------------------------------------------------------------------------
__global__ __launch_bounds__(256) void gemm2_kernel(const u16* __restrict__ Hh,
                                                    const u16* __restrict__ W2T,
                                                    const float* __restrict__ b2,
                                                    float* __restrict__ out) {
    __shared__ u16 As[64 * 32];
    __shared__ u16 Bs[NOUTP * 32];
    const int tid = threadIdx.x;
    const int m0 = blockIdx.y * 64;
    const int kc = blockIdx.x;
    const int kbase = kc * (H1DIM / KSPLIT);
    const int wave = tid >> 6;
    const int lane = tid & 63;
    const int quad = lane >> 4;
    const int l16 = lane & 15;

    f32x4 acc[7];
#pragma unroll
    for (int j = 0; j < 7; ++j) acc[j] = (f32x4){0.f, 0.f, 0.f, 0.f};

    const u16* ag = Hh + (size_t)(m0 + (tid >> 2)) * H1DIM + kbase + (tid & 3) * 8;
    u16* la = &As[tid * 8];
    const u16* bg0 = W2T + (size_t)(tid >> 2) * H1DIM + kbase + (tid & 3) * 8;
    u16* lb0 = &Bs[tid * 8];
    const int ch1 = tid + 256;
    const u16* bg1 = W2T + (size_t)(ch1 >> 2) * H1DIM + kbase + (ch1 & 3) * 8;
    u16* lb1 = &Bs[ch1 * 8];
    const bool bact = (ch1 < NOUTP * 4);

    for (int kk = 0; kk < H1DIM / KSPLIT; kk += 32) {
        gl2lds16(ag, la);
        gl2lds16(bg0, lb0);
        if (bact) gl2lds16(bg1, lb1);
        ag += 32; bg0 += 32; bg1 += 32;
        __syncthreads();

        bf16x8 af = *(const bf16x8*)&As[(wave * 16 + l16) * 32 + quad * 8];
#pragma unroll
        for (int j = 0; j < 7; ++j) {
            bf16x8 bfr = *(const bf16x8*)&Bs[(j * 16 + l16) * 32 + quad * 8];
            acc[j] = __builtin_amdgcn_mfma_f32_16x16x32_bf16(af, bfr, acc[j], 0, 0, 0);
        }
        __syncthreads();
    }

#pragma unroll
    for (int j = 0; j < 7; ++j) {
        const int col = j * 16 + l16;
        if (col < NOUT) {
            const float bv = (kc == 0) ? b2[col] : 0.f;
            const int rbase = m0 + wave * 16 + quad * 4;
#pragma unroll
            for (int r = 0; r < 4; ++r)
                atomicAdd(&out[(size_t)(rbase + r) * NOUT + col], acc[j][r] + bv);
        }
    }
}

// ---------------------------------------------------------------------------
extern "C" void kernel_launch(void* const* d_in, const int* in_sizes, int n_in,
                              void* d_out, int out_size, void* d_ws, size_t ws_size,
                              hipStream_t stream) {
    const float* inputs = (const float*)d_in[0];
    const void*  edges  = d_in[1];
    const float* gcn_w  = (const float*)d_in[2];
    const float* gcn_b  = (const float*)d_in[3];
    const float* W1     = (const float*)d_in[4];
    const float* b1     = (const float*)d_in[5];
    const float* W2     = (const float*)d_in[6];
    const float* b2     = (const float*)d_in[7];
    float* out = (float*)d_out;

    const int N = in_sizes[0];          // 8192 * 978 = 8,011,776
    const int Brows = N / NGENES;       // 8192
    const int E = in_sizes[1] / 2;      // 20,000,000

    char* ws = (char*)d_ws;
    size_t off = 0;
    auto carve = [&](size_t bytes) -> void* {
        void* p = ws + off;
        off = (off + bytes + 255) & ~(size_t)255;
        return p;
    };
    // Region 0: ebuf (172 MB), aliased by all post-scatter buffers (they are
    // first written only after pass B has consumed ebuf).
    u64* ebuf = (u64*)carve((size_t)NOCT * RSTRIDE * 8);
    char* ali = (char*)ebuf;
    auto aliascarve = [&](size_t bytes) -> void* {
        void* p = ali;
        ali += (bytes + 255) & ~(size_t)255;
        return p;
    };
    float* agg  = (float*)aliascarve((size_t)N * 4);
    u16*   Abf  = (u16*)aliascarve((size_t)Brows * KPAD * 2);
    u16*   W1T  = (u16*)aliascarve((size_t)H1DIM * KPAD * 2);
    u16*   W2Tp = (u16*)aliascarve((size_t)NOUTP * H1DIM * 2);
    u16*   H1   = (u16*)aliascarve((size_t)Brows * H1DIM * 2);
    // (87 MB used of the 172 MB region)

    int*   flag = (int*)carve(256);
    u16*   xb   = (u16*)carve((size_t)N * 2);
    u32*   cnt  = (u32*)carve((size_t)(NB + 64) * 4);   // cnt[NB], ocnt[8], ovfcnt, ovfecnt
    u32*   ocnt    = cnt + NB;
    u32*   ovfcnt  = cnt + NB + 8;
    u32*   ovfecnt = cnt + NB + 9;
    u32*   ovfg = (u32*)carve((size_t)(1 << 19) * 8);   // 4 MB pair spills
    u64*   ovfe = (u64*)carve((size_t)(1 << 18) * 8);   // 2 MB entry spills
    u32*   pairs = (u32*)carve((size_t)NB * CAP_B * 4); // 91.7 MB
    const bool use_binned = (off <= ws_size) && (N <= (NOCT << OCT_SH)) &&
                            ((char*)ali <= (char*)ebuf + (size_t)NOCT * RSTRIDE * 8);

    hipMemsetAsync(out, 0, (size_t)out_size * 4, stream);
    detect_kernel<<<1, 64, 0, stream>>>((const unsigned*)edges, flag);

    if (use_binned) {
        hipMemsetAsync(cnt, 0, (size_t)(NB + 64) * 4, stream);
        xbf_kernel<<<(N / 4 + 255) / 256, 256, 0, stream>>>(inputs, gcn_w, xb, N);
        binoct_kernel<<<NWG_A, A_THR, 0, stream>>>(edges, flag, E, ebuf, ocnt,
                                                   ovfe, ovfecnt);
        binscatter_kernel<<<SC_WGS, SC_THR, 0, stream>>>(ebuf, ocnt, xb,
                                                         pairs, cnt, ovfg, ovfcnt);
        accum_kernel<<<NB, 512, 0, stream>>>(pairs, cnt, agg);
        ovf_fix_kernel<<<8, 256, 0, stream>>>(ovfg, ovfcnt, agg);
        ovfe_fix_kernel<<<8, 256, 0, stream>>>(ovfe, ovfecnt, xb, agg);
    } else {
        hipMemsetAsync(agg, 0, (size_t)N * 4, stream);
        const int sblocks = (E + 255) / 256;
        scatter_kernel<<<sblocks, 256, 0, stream>>>(edges, inputs, gcn_w, agg, flag, E);
    }

    act_kernel<<<(Brows * KPAD) / 256, 256, 0, stream>>>(agg, gcn_b, Abf);

    transposeW1<<<dim3(H1DIM / 32, KPAD / 32), dim3(32, 8), 0, stream>>>(W1, W1T);
    transposeW2<<<dim3(4, H1DIM / 32), dim3(32, 8), 0, stream>>>(W2, W2Tp);

    gemm1_kernel<<<dim3(H1DIM / 128, Brows / 128), 256, 0, stream>>>(Abf, W1T, b1, H1);
    gemm2_kernel<<<dim3(KSPLIT, Brows / 64), 256, 0, stream>>>(H1, W2Tp, b2, out);
}

// Round 7
// 826.759 us; speedup vs baseline: 1.0577x; 1.0577x over previous
//
#include <hip/hip_runtime.h>
#include <hip/hip_bf16.h>
#include <stdint.h>

// ---------------------------------------------------------------------------
// GCN encoder: src-octant binned scatter-add -> relu -> GEMM1(978->2048)
// + relu -> GEMM2(2048->100). bf16 MFMA for both GEMMs (fp32 accumulate).
//
// R9: R8b diagnosis: pass B (XCD-pinned gather) works (~207us, was 347) but
// pass A regressed it all back: (a) nt 64B-group stores -> 2.34x write amp
// (plain stores measured 1.08x in R6); (b) per-edge LDS atomicAdd on 8
// octant counters -> 8.2M bank-conflict cycles (8-way same-address storms).
// Fix: ballot-cooperative binning (1 atomic per wave per octant, consecutive
// slots -> conflict-free stores, stA rows padded to phase-shift banks) and
// plain allocating stores for ebuf + pairs flushes.
// ---------------------------------------------------------------------------

typedef unsigned short u16;
typedef unsigned int u32;
typedef unsigned long long u64;
typedef __bf16 bf16x8 __attribute__((ext_vector_type(8)));
typedef float f32x4 __attribute__((ext_vector_type(4)));
typedef unsigned int u32x4 __attribute__((ext_vector_type(4)));

#define NGENES 978
#define KPAD   1024
#define H1DIM  2048
#define NOUT   100
#define NOUTP  112   // padded to 7 * 16
#define KSPLIT 8

// scatter binning: 8,011,776 nodes = 978 buckets x 8192 nodes (exact)
#define NB      978
#define BSH     13
#define BNODES  8192
#define SC_WGS  256     // pass B workgroups (32 per octant)
#define SC_THR  1024
#define SDEPTH  32      // pass B LDS stage depth per bucket
#define CAP_B   24576   // per-bucket pairs capacity (x16)

// src-octant binning (pass A)
#define NOCT     8
#define OCT_SH   20
#define OCT_NODES (1u << 20)
#define RSTRIDE  2686976u   // u64 entries per octant region (x8; mean 2.62M)
#define ODEPTH   512        // pass A LDS stage depth per octant
#define OPAD     (ODEPTH + 2)  // row stride: +16B phase-shifts octant banks
#define NWG_A    2048
#define A_THR    256

// round-to-nearest-even f32 -> bf16
__device__ __forceinline__ u16 f2b(float f) {
    unsigned u = __builtin_bit_cast(unsigned, f);
    u = (u + 0x7FFFu + ((u >> 16) & 1u)) >> 16;
    return (u16)u;
}

__device__ __forceinline__ u32 nt_u32(const u32* p) {
    return __builtin_nontemporal_load(p);
}
__device__ __forceinline__ float nt_f32(const float* p) {
    return __builtin_nontemporal_load(p);
}

// async 16B global -> LDS direct copy (wave-uniform base + lane*16 layout)
__device__ __forceinline__ void gl2lds16(const void* g, void* l) {
    __builtin_amdgcn_global_load_lds(
        (const __attribute__((address_space(1))) void*)(uintptr_t)g,
        (__attribute__((address_space(3))) void*)(unsigned)(uintptr_t)l,
        16, 0, 0);
}

// ---------------------------------------------------------------------------
// Detect whether edges buffer is int64 (odd 4-byte words all zero) or int32.
// ---------------------------------------------------------------------------
__global__ void detect_kernel(const unsigned* __restrict__ e, int* __restrict__ flag) {
    if (threadIdx.x == 0) {
        int is64 = 1;
        for (int i = 0; i < 64; ++i) {
            if (e[2 * i + 1] != 0u) { is64 = 0; break; }
        }
        *flag = is64;
    }
}

// ---------------------------------------------------------------------------
// xb[n] = bf16(inputs[n] * gcn_w) — the gather table (16 MB).
// ---------------------------------------------------------------------------
__global__ void xbf_kernel(const float* __restrict__ x, const float* __restrict__ gcn_w,
                           u16* __restrict__ xb, int N) {
    const float w = gcn_w[0];
    int i = (blockIdx.x * 256 + threadIdx.x) * 4;
    if (i + 3 < N) {
        float4 v = *(const float4*)&x[i];
        xb[i + 0] = f2b(v.x * w);
        xb[i + 1] = f2b(v.y * w);
        xb[i + 2] = f2b(v.z * w);
        xb[i + 3] = f2b(v.w * w);
    } else {
        for (int k = i; k < N; ++k) xb[k] = f2b(x[k] * w);
    }
}

// ---------------------------------------------------------------------------
// Pass A: stream edges, bin u64 entries ((dst<<20)|src_local) by src-octant
// (o = src>>20). Ballot-cooperative slot assignment: per octant, leader lane
// does one atomicAdd(ofill), lanes take base+rank -> consecutive slots
// (conflict-free LDS stores). Flush 8-entry 64B groups (plain stores) at
// globally reserved positions. Overflow spills losslessly to ovfe.
// ---------------------------------------------------------------------------
__global__ __launch_bounds__(A_THR) void binoct_kernel(const void* __restrict__ edges,
                                                       const int* __restrict__ flag, int E,
                                                       u64* __restrict__ ebuf,
                                                       u32* __restrict__ ocnt,
                                                       u64* __restrict__ ovfe,
                                                       u32* __restrict__ ovfecnt) {
    __shared__ u64 stA[NOCT][OPAD];     // ~33 KB
    __shared__ u32 ofill[NOCT];
    __shared__ u32 gbase[NOCT], gn[NOCT];
    const int tid = threadIdx.x;
    const int lane = tid & 63;
    if (tid < NOCT) ofill[tid] = 0;
    __syncthreads();

    const int per = (E + NWG_A - 1) / NWG_A;
    const int s = blockIdx.x * per;
    const int e = min(E, s + per);
    const u32* eb = (const u32*)edges;
    const int st = (*flag) ? 2 : 1;
    const u32* sp = eb;
    const u32* dp = eb + (size_t)st * E;

    for (int base_i = s; base_i < e; base_i += 8 * A_THR) {
        u32 sv[8], dv[8];
#pragma unroll
        for (int k = 0; k < 8; ++k) {
            int i = base_i + tid + k * A_THR;
            bool ok = i < e;
            sv[k] = ok ? nt_u32(&sp[(size_t)st * i]) : 0xFFFFFFFFu;
            dv[k] = ok ? nt_u32(&dp[(size_t)st * i]) : 0u;
        }
#pragma unroll
        for (int k = 0; k < 8; ++k) {
            const bool valid = sv[k] != 0xFFFFFFFFu;
            const u32 o = sv[k] >> OCT_SH;
            u32 slot = 0xFFFFFFFFu;
#pragma unroll
            for (u32 oct = 0; oct < NOCT; ++oct) {
                u64 mask = __ballot(valid && (o == oct));
                if (mask) {
                    int leader = __ffsll(mask) - 1;
                    u32 cnt_o = (u32)__popcll(mask);
                    u32 base = 0;
                    if (lane == leader) base = atomicAdd(&ofill[oct], cnt_o);
                    base = __shfl(base, leader, 64);
                    if (valid && o == oct)
                        slot = base + (u32)__popcll(mask & ((1ull << lane) - 1ull));
                }
            }
            if (valid) {
                if (slot < ODEPTH) {
                    stA[o][slot] = ((u64)dv[k] << OCT_SH) | (u64)(sv[k] & (OCT_NODES - 1));
                } else {   // lossless spill: (dst<<32)|src_global
                    u32 og = atomicAdd(ovfecnt, 1u);
                    ovfe[og] = ((u64)dv[k] << 32) | (u64)sv[k];
                }
            }
        }
        __syncthreads();
        if (tid < NOCT) {
            u32 f = min(ofill[tid], (u32)ODEPTH);
            u32 nl = f >> 3;
            gn[tid] = nl;
            gbase[tid] = nl ? atomicAdd(&ocnt[tid], nl << 3) : 0u;
        }
        __syncthreads();
        {
            const int b = tid >> 5;          // 256 thr -> 8 bins x 32 lanes
            const u32 g0 = tid & 31;
            for (u32 g = g0; g < gn[b]; g += 32) {
                u32 base = gbase[b] + (g << 3);
                if (base < RSTRIDE) {
                    u64* dst = &ebuf[(size_t)b * RSTRIDE + base];
#pragma unroll
                    for (int q = 0; q < 4; ++q) {
                        u64 w0 = stA[b][g * 8 + q * 2];
                        u64 w1 = stA[b][g * 8 + q * 2 + 1];
                        u32x4 v;
                        v.x = (u32)w0; v.y = (u32)(w0 >> 32);
                        v.z = (u32)w1; v.w = (u32)(w1 >> 32);
                        *(u32x4*)&dst[q * 2] = v;
                    }
                } else {   // region capacity spill (~never)
                    for (int q = 0; q < 8; ++q) {
                        u64 ent = stA[b][g * 8 + q];
                        u32 d = (u32)(ent >> OCT_SH);
                        u32 srcg = ((u32)b << OCT_SH) | ((u32)ent & (OCT_NODES - 1));
                        u32 og = atomicAdd(ovfecnt, 1u);
                        ovfe[og] = ((u64)d << 32) | (u64)srcg;
                    }
                }
            }
        }
        __syncthreads();
        if (tid < NOCT) {
            u32 f = min(ofill[tid], (u32)ODEPTH);
            u32 n8 = gn[tid] << 3;
            for (u32 r = n8; r < f; ++r) stA[tid][r - n8] = stA[tid][r];
            ofill[tid] = f - n8;
        }
        __syncthreads();
    }
    // tail: one sentinel-padded group per octant (keeps cursor x8-aligned)
    if (tid < NOCT) {
        u32 f = min(ofill[tid], (u32)ODEPTH);   // <= 7
        if (f) {
            u32 base = atomicAdd(&ocnt[tid], 8u);
            if (base < RSTRIDE) {
                u64* dst = &ebuf[(size_t)tid * RSTRIDE + base];
                for (u32 q = 0; q < 8; ++q)
                    dst[q] = (q < f) ? stA[tid][q] : ~0ull;
            } else {
                for (u32 q = 0; q < f; ++q) {
                    u64 ent = stA[tid][q];
                    u32 d = (u32)(ent >> OCT_SH);
                    u32 srcg = ((u32)tid << OCT_SH) | ((u32)ent & (OCT_NODES - 1));
                    u32 og = atomicAdd(ovfecnt, 1u);
                    ovfe[og] = ((u64)d << 32) | (u64)srcg;
                }
            }
        }
    }
}

// ---------------------------------------------------------------------------
// Pass B: per-octant gather + dst-bin. bid%8 = octant (XCD-pinned -> 2MB xb
// slice is L2-resident). Entry stream nt loads; pairs flushed as 64B plain
// stores at globally reserved positions. Hole-race-free overflow -> ovfg.
// ---------------------------------------------------------------------------
__global__ __launch_bounds__(SC_THR) void binscatter_kernel(const u64* __restrict__ ebuf,
                                                            const u32* __restrict__ ocnt,
                                                            const u16* __restrict__ xb,
                                                            u32* __restrict__ pairs,
                                                            u32* __restrict__ cnt,
                                                            u32* __restrict__ ovfg,
                                                            u32* __restrict__ ovfcnt) {
    __shared__ u32 sfill[NB];
    __shared__ u32 stage[SDEPTH * NB];      // transposed [slot][bucket], 125 KB
    const int tid = threadIdx.x;
    for (int b = tid; b < NB; b += SC_THR) sfill[b] = 0;
    __syncthreads();

    const int o = blockIdx.x & 7;           // XCD pin
    const int sub = blockIdx.x >> 3;        // 0..31
    u32 n = ocnt[o]; if (n > RSTRIDE) n = RSTRIDE;
    const u64* eo = ebuf + (size_t)o * RSTRIDE;
    const u16* xbo = xb + ((size_t)o << OCT_SH);
    const u32 per = (n + 31) / 32;
    const u32 s = sub * per;
    const u32 e = min(n, s + per);

    for (u32 base_i = s; base_i < e; base_i += 8 * SC_THR) {
        u64 ev[8];
#pragma unroll
        for (int k = 0; k < 8; ++k) {
            u32 i = base_i + tid + k * SC_THR;
            ev[k] = (i < e) ? __builtin_nontemporal_load(&eo[i]) : ~0ull;
        }
        u32 d[8];
        u16 val[8];
#pragma unroll
        for (int k = 0; k < 8; ++k) {
            d[k] = (u32)(ev[k] >> OCT_SH);
            val[k] = (ev[k] != ~0ull) ? xbo[(u32)ev[k] & (OCT_NODES - 1)] : (u16)0;
        }
#pragma unroll
        for (int h = 0; h < 2; ++h) {
#pragma unroll
            for (int k = 4 * h; k < 4 * h + 4; ++k) {
                if (ev[k] != ~0ull) {
                    u32 b = d[k] >> BSH;
                    u32 pr = ((d[k] & (BNODES - 1)) << 16) | (u32)val[k];
                    u32 slot = atomicAdd(&sfill[b], 1u);
                    if (slot < SDEPTH) {
                        stage[slot * NB + b] = pr;
                    } else {   // lossless spill (dst_global, val)
                        u32 og = atomicAdd(ovfcnt, 1u);
                        ovfg[og * 2] = d[k];
                        ovfg[og * 2 + 1] = pr & 0xFFFFu;
                    }
                }
            }
            __syncthreads();
            for (int b = tid; b < NB; b += SC_THR) {
                u32 f = min(sfill[b], (u32)SDEPTH);   // clamp inflation
                u32 nl = f >> 4;
                if (nl) {
                    u32 base = atomicAdd(&cnt[b], nl << 4);
                    for (u32 g = 0; g < nl; ++g) {
                        u32 wb = base + (g << 4);
                        if (wb < CAP_B) {
                            u32* dst = &pairs[(size_t)b * CAP_B + wb];
#pragma unroll
                            for (int q = 0; q < 4; ++q) {
                                u32x4 v;
                                v.x = stage[(g * 16 + q * 4 + 0) * NB + b];
                                v.y = stage[(g * 16 + q * 4 + 1) * NB + b];
                                v.z = stage[(g * 16 + q * 4 + 2) * NB + b];
                                v.w = stage[(g * 16 + q * 4 + 3) * NB + b];
                                *(u32x4*)&dst[q * 4] = v;
                            }
                        } else {
                            for (int q = 0; q < 16; ++q) {
                                u32 pr = stage[(g * 16 + q) * NB + b];
                                u32 og = atomicAdd(ovfcnt, 1u);
                                ovfg[og * 2] = ((u32)b << BSH) | (pr >> 16);
                                ovfg[og * 2 + 1] = pr & 0xFFFFu;
                            }
                        }
                    }
                    u32 n16 = nl << 4;
                    u32 rem = f - n16;
                    for (u32 r = 0; r < rem; ++r)
                        stage[r * NB + b] = stage[(n16 + r) * NB + b];
                    sfill[b] = rem;
                } else {
                    sfill[b] = f;
                }
            }
            __syncthreads();
        }
    }
    // tail: flush remainder, zero-padded to x16 groups
    for (int b = tid; b < NB; b += SC_THR) {
        u32 f = min(sfill[b], (u32)SDEPTH);
        if (f) {
            u32 padded = (f + 15u) & ~15u;
            u32 base = atomicAdd(&cnt[b], padded);
            for (u32 g = 0; g < (padded >> 4); ++g) {
                u32 wb = base + (g << 4);
                if (wb < CAP_B) {
                    u32* dst = &pairs[(size_t)b * CAP_B + wb];
#pragma unroll
                    for (int q = 0; q < 4; ++q) {
                        u32x4 v;
                        u32 j = g * 16 + q * 4;
                        v.x = (j + 0 < f) ? stage[(j + 0) * NB + b] : 0u;
                        v.y = (j + 1 < f) ? stage[(j + 1) * NB + b] : 0u;
                        v.z = (j + 2 < f) ? stage[(j + 2) * NB + b] : 0u;
                        v.w = (j + 3 < f) ? stage[(j + 3) * NB + b] : 0u;
                        *(u32x4*)&dst[q * 4] = v;
                    }
                } else {
                    for (u32 q = g * 16; q < f && q < g * 16 + 16; ++q) {
                        u32 pr = stage[q * NB + b];
                        u32 og = atomicAdd(ovfcnt, 1u);
                        ovfg[og * 2] = ((u32)b << BSH) | (pr >> 16);
                        ovfg[og * 2 + 1] = pr & 0xFFFFu;
                    }
                }
            }
        }
    }
}

// ---------------------------------------------------------------------------
// Accum: per-bucket LDS fp32 tile, stream pairs (nt), write agg.
// ---------------------------------------------------------------------------
__global__ __launch_bounds__(512) void accum_kernel(const u32* __restrict__ pairs,
                                                    const u32* __restrict__ cnt,
                                                    float* __restrict__ agg) {
    __shared__ float acc[BNODES];    // 32 KB
    for (int i = threadIdx.x; i < BNODES; i += 512) acc[i] = 0.f;
    __syncthreads();
    const int b = blockIdx.x;
    u32 n = cnt[b];
    if (n > CAP_B) n = CAP_B;
    const u32 p0 = (u32)b * CAP_B;
    const u32 p1 = p0 + n;
    u32 p = p0 + threadIdx.x;
    for (; p + 3 * 512 < p1; p += 4 * 512) {
        u32 pk[4];
#pragma unroll
        for (int k = 0; k < 4; ++k) pk[k] = nt_u32(&pairs[p + k * 512]);
#pragma unroll
        for (int k = 0; k < 4; ++k) {
            if (pk[k]) {
                float v = __builtin_bit_cast(float, (pk[k] & 0xFFFFu) << 16);
                atomicAdd(&acc[pk[k] >> 16], v);
            }
        }
    }
    for (; p < p1; p += 512) {
        u32 pk = nt_u32(&pairs[p]);
        if (pk) {
            float v = __builtin_bit_cast(float, (pk & 0xFFFFu) << 16);
            atomicAdd(&acc[pk >> 16], v);
        }
    }
    __syncthreads();
    const size_t node0 = (size_t)b << BSH;
    for (int i = threadIdx.x; i < BNODES; i += 512) agg[node0 + i] = acc[i];
}

// ---------------------------------------------------------------------------
// Spill cleanups (run after accum; normally zero entries).
// ---------------------------------------------------------------------------
__global__ void ovf_fix_kernel(const u32* __restrict__ ovfg, const u32* __restrict__ ovfcnt,
                               float* __restrict__ agg) {
    u32 n = *ovfcnt;
    for (u32 i = blockIdx.x * 256 + threadIdx.x; i < n; i += gridDim.x * 256) {
        float v = __builtin_bit_cast(float, ovfg[i * 2 + 1] << 16);
        atomicAdd(&agg[ovfg[i * 2]], v);
    }
}

__global__ void ovfe_fix_kernel(const u64* __restrict__ ovfe, const u32* __restrict__ ovfecnt,
                                const u16* __restrict__ xb, float* __restrict__ agg) {
    u32 n = *ovfecnt;
    for (u32 i = blockIdx.x * 256 + threadIdx.x; i < n; i += gridDim.x * 256) {
        u64 ev = ovfe[i];
        u32 srcg = (u32)ev;
        u32 d = (u32)(ev >> 32);
        float v = __builtin_bit_cast(float, ((u32)xb[srcg]) << 16);
        atomicAdd(&agg[d], v);
    }
}

// ---------------------------------------------------------------------------
// Legacy direct-atomic scatter (fallback if workspace too small).
// ---------------------------------------------------------------------------
__global__ void scatter_kernel(const void* __restrict__ edges, const float* __restrict__ x,
                               const float* __restrict__ gcn_w, float* __restrict__ agg,
                               const int* __restrict__ flag, int E) {
    long long e = (long long)blockIdx.x * 256 + threadIdx.x;
    if (e >= E) return;
    int s, d;
    if (*flag) {
        const long long* e64 = (const long long*)edges;
        s = (int)e64[e];
        d = (int)e64[(long long)E + e];
    } else {
        const int* e32 = (const int*)edges;
        s = e32[e];
        d = e32[(long long)E + e];
    }
    atomicAdd(&agg[d], x[s] * gcn_w[0]);
}

// ---------------------------------------------------------------------------
// Fused bias + relu + bf16 convert, pad K 978 -> 1024 with zeros.
// ---------------------------------------------------------------------------
__global__ void act_kernel(const float* __restrict__ agg, const float* __restrict__ gcn_b,
                           u16* __restrict__ A) {
    int idx = blockIdx.x * 256 + threadIdx.x;
    int i = idx >> 10;         // KPAD = 1024
    int k = idx & 1023;
    float v = 0.f;
    if (k < NGENES) {
        v = nt_f32(&agg[(size_t)i * NGENES + k]) + gcn_b[0];
        v = v > 0.f ? v : 0.f;
    }
    A[idx] = f2b(v);
}

// ---------------------------------------------------------------------------
// W1 [978][2048] f32 -> W1T [2048][1024] bf16 (transposed, K zero-padded)
// ---------------------------------------------------------------------------
__global__ void transposeW1(const float* __restrict__ W1, u16* __restrict__ W1T) {
    __shared__ float t[32][33];
    int n0 = blockIdx.x * 32;
    int k0 = blockIdx.y * 32;
    int tx = threadIdx.x, ty = threadIdx.y;
    for (int r = ty; r < 32; r += 8) {
        int k = k0 + r;
        t[r][tx] = (k < NGENES) ? W1[(size_t)k * H1DIM + n0 + tx] : 0.f;
    }
    __syncthreads();
    for (int r = ty; r < 32; r += 8) {
        int n = n0 + r;
        W1T[(size_t)n * KPAD + k0 + tx] = f2b(t[tx][r]);
    }
}

// ---------------------------------------------------------------------------
// W2 [2048][100] f32 -> W2T [112][2048] bf16 (transposed, N zero-padded)
// ---------------------------------------------------------------------------
__global__ void transposeW2(const float* __restrict__ W2, u16* __restrict__ W2T) {
    __shared__ float t[32][33];
    int n0 = blockIdx.x * 32;
    int k0 = blockIdx.y * 32;
    int tx = threadIdx.x, ty = threadIdx.y;
    for (int r = ty; r < 32; r += 8) {
        int k = k0 + r;
        int n = n0 + tx;
        t[r][tx] = (n < NOUT) ? W2[(size_t)k * NOUT + n] : 0.f;
    }
    __syncthreads();
    for (int r = ty; r < 32; r += 8) {
        int n = n0 + r;
        if (n < NOUTP) W2T[(size_t)n * H1DIM + k0 + tx] = f2b(t[tx][r]);
    }
}

// ---------------------------------------------------------------------------
// GEMM1: H[8192][2048] = relu(A[8192][1024] @ W1T^T + b1), bf16 out.
// ---------------------------------------------------------------------------
__global__ __launch_bounds__(256) void gemm1_kernel(const u16* __restrict__ A,
                                                    const u16* __restrict__ Bt,
                                                    const float* __restrict__ b1,
                                                    u16* __restrict__ H) {
    __shared__ u16 As[128 * 32];
    __shared__ u16 Bs[128 * 32];
    const int tid = threadIdx.x;
    const int m0 = blockIdx.y * 128;
    const int n0 = blockIdx.x * 128;
    const int wave = tid >> 6;
    const int lane = tid & 63;
    const int wm = (wave >> 1) * 64;
    const int wn = (wave & 1) * 64;
    const int quad = lane >> 4;
    const int l16 = lane & 15;

    f32x4 acc[4][4];
#pragma unroll
    for (int i = 0; i < 4; ++i)
#pragma unroll
        for (int j = 0; j < 4; ++j)
            acc[i][j] = (f32x4){0.f, 0.f, 0.f, 0.f};

    const int ch0 = tid, ch1 = tid + 256;
    const u16* ag0 = A + (size_t)(m0 + (ch0 >> 2)) * KPAD + (ch0 & 3) * 8;
    const u16* ag1 = A + (size_t)(m0 + (ch1 >> 2)) * KPAD + (ch1 & 3) * 8;
    const u16* bg0 = Bt + (size_t)(n0 + (ch0 >> 2)) * KPAD + (ch0 & 3) * 8;
    const u16* bg1 = Bt + (size_t)(n0 + (ch1 >> 2)) * KPAD + (ch1 & 3) * 8;
    u16* la0 = &As[ch0 * 8];
    u16* la1 = &As[ch1 * 8];
    u16* lb0 = &Bs[ch0 * 8];
    u16* lb1 = &Bs[ch1 * 8];

    for (int k0 = 0; k0 < KPAD; k0 += 32) {
        gl2lds16(ag0, la0);
        gl2lds16(ag1, la1);
        gl2lds16(bg0, lb0);
        gl2lds16(bg1, lb1);
        ag0 += 32; ag1 += 32; bg0 += 32; bg1 += 32;
        __syncthreads();

        bf16x8 af[4], bfr[4];
#pragma unroll
        for (int i = 0; i < 4; ++i)
            af[i] = *(const bf16x8*)&As[(wm + i * 16 + l16) * 32 + quad * 8];
#pragma unroll
        for (int j = 0; j < 4; ++j)
            bfr[j] = *(const bf16x8*)&Bs[(wn + j * 16 + l16) * 32 + quad * 8];
#pragma unroll
        for (int i = 0; i < 4; ++i)
#pragma unroll
            for (int j = 0; j < 4; ++j)
                acc[i][j] = __builtin_amdgcn_mfma_f32_16x16x32_bf16(af[i], bfr[j], acc[i][j], 0, 0, 0);
        __syncthreads();
    }

#pragma unroll
    for (int j = 0; j < 4; ++j) {
        const int col = n0 + wn + j * 16 + l16;
        const float bv = b1[col];
#pragma unroll
        for (int i = 0; i < 4; ++i) {
            const int rbase = m0 + wm + i * 16 + quad * 4;
#pragma unroll
            for (int r = 0; r < 4; ++r) {
                float v = acc[i][j][r] + bv;
                v = v > 0.f ? v : 0.f;
                H[(size_t)(rbase + r) * H1DIM + col] = f2b(v);
            }
        }
    }
}

// ---------------------------------------------------------------------------
// GEMM2: out[8192][100] += H[8192][2048] @ W2T^T + b2, split-K with atomics.
// ---------------------------------------------------------------------------
__global__ __launch_bounds__(256) void gemm2_kernel(const u16* __restrict__ Hh,
                                                    const u16* __restrict__ W2T,
                                                    const float* __restrict__ b2,
                                                    float* __restrict__ out) {
    __shared__ u16 As[64 * 32];
    __shared__ u16 Bs[NOUTP * 32];
    const int tid = threadIdx.x;
    const int m0 = blockIdx.y * 64;
    const int kc = blockIdx.x;
    const int kbase = kc * (H1DIM / KSPLIT);
    const int wave = tid >> 6;
    const int lane = tid & 63;
    const int quad = lane >> 4;
    const int l16 = lane & 15;

    f32x4 acc[7];
#pragma unroll
    for (int j = 0; j < 7; ++j) acc[j] = (f32x4){0.f, 0.f, 0.f, 0.f};

    const u16* ag = Hh + (size_t)(m0 + (tid >> 2)) * H1DIM + kbase + (tid & 3) * 8;
    u16* la = &As[tid * 8];
    const u16* bg0 = W2T + (size_t)(tid >> 2) * H1DIM + kbase + (tid & 3) * 8;
    u16* lb0 = &Bs[tid * 8];
    const int ch1 = tid + 256;
    const u16* bg1 = W2T + (size_t)(ch1 >> 2) * H1DIM + kbase + (ch1 & 3) * 8;
    u16* lb1 = &Bs[ch1 * 8];
    const bool bact = (ch1 < NOUTP * 4);

    for (int kk = 0; kk < H1DIM / KSPLIT; kk += 32) {
        gl2lds16(ag, la);
        gl2lds16(bg0, lb0);
        if (bact) gl2lds16(bg1, lb1);
        ag += 32; bg0 += 32; bg1 += 32;
        __syncthreads();

        bf16x8 af = *(const bf16x8*)&As[(wave * 16 + l16) * 32 + quad * 8];
#pragma unroll
        for (int j = 0; j < 7; ++j) {
            bf16x8 bfr = *(const bf16x8*)&Bs[(j * 16 + l16) * 32 + quad * 8];
            acc[j] = __builtin_amdgcn_mfma_f32_16x16x32_bf16(af, bfr, acc[j], 0, 0, 0);
        }
        __syncthreads();
    }

#pragma unroll
    for (int j = 0; j < 7; ++j) {
        const int col = j * 16 + l16;
        if (col < NOUT) {
            const float bv = (kc == 0) ? b2[col] : 0.f;
            const int rbase = m0 + wave * 16 + quad * 4;
#pragma unroll
            for (int r = 0; r < 4; ++r)
                atomicAdd(&out[(size_t)(rbase + r) * NOUT + col], acc[j][r] + bv);
        }
    }
}

// ---------------------------------------------------------------------------
extern "C" void kernel_launch(void* const* d_in, const int* in_sizes, int n_in,
                              void* d_out, int out_size, void* d_ws, size_t ws_size,
                              hipStream_t stream) {
    const float* inputs = (const float*)d_in[0];
    const void*  edges  = d_in[1];
    const float* gcn_w  = (const float*)d_in[2];
    const float* gcn_b  = (const float*)d_in[3];
    const float* W1     = (const float*)d_in[4];
    const float* b1     = (const float*)d_in[5];
    const float* W2     = (const float*)d_in[6];
    const float* b2     = (const float*)d_in[7];
    float* out = (float*)d_out;

    const int N = in_sizes[0];          // 8192 * 978 = 8,011,776
    const int Brows = N / NGENES;       // 8192
    const int E = in_sizes[1] / 2;      // 20,000,000

    char* ws = (char*)d_ws;
    size_t off = 0;
    auto carve = [&](size_t bytes) -> void* {
        void* p = ws + off;
        off = (off + bytes + 255) & ~(size_t)255;
        return p;
    };
    // Region 0: ebuf (172 MB), aliased by all post-scatter buffers (they are
    // first written only after pass B has consumed ebuf).
    u64* ebuf = (u64*)carve((size_t)NOCT * RSTRIDE * 8);
    char* ali = (char*)ebuf;
    auto aliascarve = [&](size_t bytes) -> void* {
        void* p = ali;
        ali += (bytes + 255) & ~(size_t)255;
        return p;
    };
    float* agg  = (float*)aliascarve((size_t)N * 4);
    u16*   Abf  = (u16*)aliascarve((size_t)Brows * KPAD * 2);
    u16*   W1T  = (u16*)aliascarve((size_t)H1DIM * KPAD * 2);
    u16*   W2Tp = (u16*)aliascarve((size_t)NOUTP * H1DIM * 2);
    u16*   H1   = (u16*)aliascarve((size_t)Brows * H1DIM * 2);
    // (87 MB used of the 172 MB region)

    int*   flag = (int*)carve(256);
    u16*   xb   = (u16*)carve((size_t)N * 2);
    u32*   cnt  = (u32*)carve((size_t)(NB + 64) * 4);   // cnt[NB], ocnt[8], ovfcnt, ovfecnt
    u32*   ocnt    = cnt + NB;
    u32*   ovfcnt  = cnt + NB + 8;
    u32*   ovfecnt = cnt + NB + 9;
    u32*   ovfg = (u32*)carve((size_t)(1 << 19) * 8);   // 4 MB pair spills
    u64*   ovfe = (u64*)carve((size_t)(1 << 18) * 8);   // 2 MB entry spills
    u32*   pairs = (u32*)carve((size_t)NB * CAP_B * 4); // 91.7 MB
    const bool use_binned = (off <= ws_size) && (N <= (NOCT << OCT_SH)) &&
                            ((char*)ali <= (char*)ebuf + (size_t)NOCT * RSTRIDE * 8);

    hipMemsetAsync(out, 0, (size_t)out_size * 4, stream);
    detect_kernel<<<1, 64, 0, stream>>>((const unsigned*)edges, flag);

    if (use_binned) {
        hipMemsetAsync(cnt, 0, (size_t)(NB + 64) * 4, stream);
        xbf_kernel<<<(N / 4 + 255) / 256, 256, 0, stream>>>(inputs, gcn_w, xb, N);
        binoct_kernel<<<NWG_A, A_THR, 0, stream>>>(edges, flag, E, ebuf, ocnt,
                                                   ovfe, ovfecnt);
        binscatter_kernel<<<SC_WGS, SC_THR, 0, stream>>>(ebuf, ocnt, xb,
                                                         pairs, cnt, ovfg, ovfcnt);
        accum_kernel<<<NB, 512, 0, stream>>>(pairs, cnt, agg);
        ovf_fix_kernel<<<8, 256, 0, stream>>>(ovfg, ovfcnt, agg);
        ovfe_fix_kernel<<<8, 256, 0, stream>>>(ovfe, ovfecnt, xb, agg);
    } else {
        hipMemsetAsync(agg, 0, (size_t)N * 4, stream);
        const int sblocks = (E + 255) / 256;
        scatter_kernel<<<sblocks, 256, 0, stream>>>(edges, inputs, gcn_w, agg, flag, E);
    }

    act_kernel<<<(Brows * KPAD) / 256, 256, 0, stream>>>(agg, gcn_b, Abf);

    transposeW1<<<dim3(H1DIM / 32, KPAD / 32), dim3(32, 8), 0, stream>>>(W1, W1T);
    transposeW2<<<dim3(4, H1DIM / 32), dim3(32, 8), 0, stream>>>(W2, W2Tp);

    gemm1_kernel<<<dim3(H1DIM / 128, Brows / 128), 256, 0, stream>>>(Abf, W1T, b1, H1);
    gemm2_kernel<<<dim3(KSPLIT, Brows / 64), 256, 0, stream>>>(H1, W2Tp, b2, out);
}